// Round 4
// baseline (24.404 us; speedup 1.0000x reference)
//
#include <hip/hip_runtime.h>

// DeepFM fused forward, round 4.
// grid=512 (2 blocks/CU) x T=256 (4 waves); EPB=4 rows/block.
// Register double-buffered weight pipeline per layer; chunk-0 weight loads
// issued BEFORE the preceding barrier so L2 latency overlaps the drain.
// 2 cols x 2 rows per thread -> 8 FMA per LDS b128 read.

#define NF   8
#define ED   16
#define IN0  128
#define N1   256
#define N2   128
#define N3   64
#define EPB  4
#define T    256

__device__ const int g_off[NF] = {0, 50000, 55000, 57000, 58000, 59000, 59500, 59800};

// load CH float2 weights (stride ldw floats) for chunk ch into buf
#define LOADW2(buf, wp, ldw, ch, CH) { \
    _Pragma("unroll") for (int i_ = 0; i_ < (CH); ++i_) \
        (buf)[i_] = *(const float2*)((wp) + ((ch) * (CH) + i_) * (ldw)); }

__global__ __launch_bounds__(T, 2) void deepfm_fused(
    const int*   __restrict__ x,     // [B, NF]
    const float* __restrict__ emb,   // [60000, 16]
    const float* __restrict__ wlin,  // [60000]
    const float* __restrict__ blin,  // [1]
    const float* __restrict__ w1,    // [128, 256]
    const float* __restrict__ b1,    // [256]
    const float* __restrict__ w2,    // [256, 128]
    const float* __restrict__ b2,    // [128]
    const float* __restrict__ w3,    // [128, 64]
    const float* __restrict__ b3,    // [64]
    const float* __restrict__ wlast, // [64]
    float*       __restrict__ out)   // [B]
{
    __shared__ float h0[EPB][IN0];      // 2 KB
    __shared__ float h1[EPB][N1];       // 4 KB
    __shared__ float h2[EPB][N2];       // 2 KB
    __shared__ float ps2[EPB][N2];      // 2 KB  (L2 kh=1 partials)
    __shared__ float ps3[2][EPB][N3];   // 2 KB  (L3 partials)
    __shared__ float base[EPB];

    const int tid = threadIdx.x;
    const int b0  = blockIdx.x * EPB;

    // ---- L1 ownership: 2 cols (c2, c2+1), 2 rows (r0, r1) ----
    const int c2 = (tid & 127) * 2;
    const int rg = tid >> 7;
    const int r0 = rg * 2, r1 = rg * 2 + 1;
    const float* w1p = w1 + c2;

    float2 wA[32], wB[32];

    // issue L1 chunk-0 weight loads FIRST (independent of everything)
    LOADW2(wA, w1p, N1, 0, 32);

    // ---- embedding gather: 256 threads x float2 ----
    {
        const int r = tid >> 6, f = (tid >> 3) & 7, p = tid & 7;
        const int idx = x[(b0 + r) * NF + f] + g_off[f];
        *(float2*)(&h0[r][f * ED + p * 2]) = *(const float2*)(emb + idx * ED + p * 2);
    }

    // ---- sparse linear: wave 0 lanes 0..31 ----
    if (tid < 32) {
        const int r = tid >> 3, f = tid & 7;
        float lin = wlin[x[(b0 + r) * NF + f] + g_off[f]];
        lin += __shfl_xor(lin, 1);
        lin += __shfl_xor(lin, 2);
        lin += __shfl_xor(lin, 4);
        if (f == 0) base[r] = lin + blin[0];
    }

    const float2 bb1 = *(const float2*)(b1 + c2);
    __syncthreads();   // B1: h0 + base ready (w1 chunk0 drained here too)

    // ---- FM second-order: wave 0 (same wave as linear/finale -> ordered) ----
    if (tid < 64) {
        const int r = tid >> 4, d = tid & 15;
        float s = 0.0f, ss = 0.0f;
        #pragma unroll
        for (int f = 0; f < NF; ++f) {
            const float v = h0[r][f * ED + d];
            s += v;
            ss = fmaf(v, v, ss);
        }
        float p = 0.5f * (s * s - ss);
        p += __shfl_xor(p, 1);
        p += __shfl_xor(p, 2);
        p += __shfl_xor(p, 4);
        p += __shfl_xor(p, 8);
        if (d == 0) base[r] += p;
    }

    // ---- layer 1: K=128, double-buffered chunks of 32 ----
    float a00 = bb1.x, a01 = bb1.y, a10 = bb1.x, a11 = bb1.y;

    #define FMAW1(buf, ch) { \
        _Pragma("unroll") for (int i_ = 0; i_ < 32; i_ += 4) { \
            const float4 ha = *(const float4*)(&h0[r0][(ch) * 32 + i_]); \
            const float4 hb = *(const float4*)(&h0[r1][(ch) * 32 + i_]); \
            _Pragma("unroll") for (int j_ = 0; j_ < 4; ++j_) { \
                const float fa = ((const float*)&ha)[j_]; \
                const float fb = ((const float*)&hb)[j_]; \
                const float2 w = (buf)[i_ + j_]; \
                a00 = fmaf(fa, w.x, a00); a01 = fmaf(fa, w.y, a01); \
                a10 = fmaf(fb, w.x, a10); a11 = fmaf(fb, w.y, a11); } } }

    LOADW2(wB, w1p, N1, 1, 32); FMAW1(wA, 0);
    LOADW2(wA, w1p, N1, 2, 32); FMAW1(wB, 1);
    LOADW2(wB, w1p, N1, 3, 32); FMAW1(wA, 2);
    FMAW1(wB, 3);

    *(float2*)(&h1[r0][c2]) = make_float2(fmaxf(a00, 0.f), fmaxf(a01, 0.f));
    *(float2*)(&h1[r1][c2]) = make_float2(fmaxf(a10, 0.f), fmaxf(a11, 0.f));

    // ---- layer 2 ownership: 2 cols, 2 rows, 2-way K-split ----
    const int c2b = (tid & 63) * 2;
    const int rg2 = (tid >> 6) & 1;
    const int kh  = tid >> 7;            // K-half: 0 -> k 0..127, 1 -> 128..255
    const int r20 = rg2 * 2, r21 = rg2 * 2 + 1;
    const float* w2p = w2 + kh * 128 * N2 + c2b;

    // prefetch L2 chunk-0 before the barrier
    LOADW2(wA, w2p, N2, 0, 32);
    __syncthreads();   // B2: h1 ready

    float b00 = 0.f, b01 = 0.f, b10 = 0.f, b11 = 0.f;

    #define FMAW2(buf, ch) { \
        _Pragma("unroll") for (int i_ = 0; i_ < 32; i_ += 4) { \
            const float4 ha = *(const float4*)(&h1[r20][kh * 128 + (ch) * 32 + i_]); \
            const float4 hb = *(const float4*)(&h1[r21][kh * 128 + (ch) * 32 + i_]); \
            _Pragma("unroll") for (int j_ = 0; j_ < 4; ++j_) { \
                const float fa = ((const float*)&ha)[j_]; \
                const float fb = ((const float*)&hb)[j_]; \
                const float2 w = (buf)[i_ + j_]; \
                b00 = fmaf(fa, w.x, b00); b01 = fmaf(fa, w.y, b01); \
                b10 = fmaf(fb, w.x, b10); b11 = fmaf(fb, w.y, b11); } } }

    LOADW2(wB, w2p, N2, 1, 32); FMAW2(wA, 0);
    LOADW2(wA, w2p, N2, 2, 32); FMAW2(wB, 1);
    LOADW2(wB, w2p, N2, 3, 32); FMAW2(wA, 2);
    FMAW2(wB, 3);

    if (kh == 1) {
        *(float2*)(&ps2[r20][c2b]) = make_float2(b00, b01);
        *(float2*)(&ps2[r21][c2b]) = make_float2(b10, b11);
    }
    __syncthreads();   // B3: ps2 ready
    if (kh == 0) {
        const float2 bb2 = *(const float2*)(b2 + c2b);
        const float2 q0 = *(const float2*)(&ps2[r20][c2b]);
        const float2 q1 = *(const float2*)(&ps2[r21][c2b]);
        *(float2*)(&h2[r20][c2b]) = make_float2(fmaxf(b00 + q0.x + bb2.x, 0.f),
                                                fmaxf(b01 + q0.y + bb2.y, 0.f));
        *(float2*)(&h2[r21][c2b]) = make_float2(fmaxf(b10 + q1.x + bb2.x, 0.f),
                                                fmaxf(b11 + q1.y + bb2.y, 0.f));
    }

    // ---- layer 3 ownership: 1 col, 2 rows, 2-way K-split ----
    const int c3  = tid & 63;
    const int rg3 = (tid >> 6) & 1;
    const int kh3 = tid >> 7;
    const int r30 = rg3 * 2, r31 = rg3 * 2 + 1;
    const float* w3p = w3 + kh3 * 64 * N3 + c3;

    float wsA[32], wsB[32];
    // prefetch L3 chunk-0 before the barrier
    #pragma unroll
    for (int i_ = 0; i_ < 32; ++i_) wsA[i_] = w3p[i_ * N3];
    __syncthreads();   // B4: h2 ready

    float c0 = 0.f, c1 = 0.f;

    #define FMAW3(buf, ch) { \
        _Pragma("unroll") for (int i_ = 0; i_ < 32; i_ += 4) { \
            const float4 ha = *(const float4*)(&h2[r30][kh3 * 64 + (ch) * 32 + i_]); \
            const float4 hb = *(const float4*)(&h2[r31][kh3 * 64 + (ch) * 32 + i_]); \
            _Pragma("unroll") for (int j_ = 0; j_ < 4; ++j_) { \
                const float fa = ((const float*)&ha)[j_]; \
                const float fb = ((const float*)&hb)[j_]; \
                c0 = fmaf(fa, (buf)[i_ + j_], c0); \
                c1 = fmaf(fb, (buf)[i_ + j_], c1); } } }

    #pragma unroll
    for (int i_ = 0; i_ < 32; ++i_) wsB[i_] = w3p[(32 + i_) * N3];
    FMAW3(wsA, 0);
    FMAW3(wsB, 1);

    ps3[kh3][r30][c3] = c0;
    ps3[kh3][r31][c3] = c1;
    __syncthreads();   // B5: ps3 ready

    // ---- finale: wave 0 ----
    if (tid < 64) {
        const int c = tid;
        const float bb = b3[c];
        const float wl = wlast[c];
        float t[EPB];
        #pragma unroll
        for (int r = 0; r < EPB; ++r) {
            const float v = ps3[0][r][c] + ps3[1][r][c] + bb;
            t[r] = fmaxf(v, 0.f) * wl;
        }
        #pragma unroll
        for (int off = 1; off < 64; off <<= 1) {
            #pragma unroll
            for (int r = 0; r < EPB; ++r) t[r] += __shfl_xor(t[r], off);
        }
        if (tid == 0) {
            #pragma unroll
            for (int r = 0; r < EPB; ++r) out[b0 + r] = base[r] + t[r];
        }
    }
}

extern "C" void kernel_launch(void* const* d_in, const int* in_sizes, int n_in,
                              void* d_out, int out_size, void* d_ws, size_t ws_size,
                              hipStream_t stream) {
    const int*   x     = (const int*)d_in[0];
    const float* emb   = (const float*)d_in[1];
    const float* wlin  = (const float*)d_in[2];
    const float* blin  = (const float*)d_in[3];
    const float* w1    = (const float*)d_in[4];
    const float* b1    = (const float*)d_in[5];
    const float* w2    = (const float*)d_in[6];
    const float* b2    = (const float*)d_in[7];
    const float* w3    = (const float*)d_in[8];
    const float* b3    = (const float*)d_in[9];
    const float* wlast = (const float*)d_in[10];
    float* out = (float*)d_out;

    const int batch = in_sizes[0] / NF;   // 2048
    dim3 grid(batch / EPB);               // 512 blocks x 256 threads
    deepfm_fused<<<grid, T, 0, stream>>>(x, emb, wlin, blin,
                                         w1, b1, w2, b2, w3, b3, wlast, out);
}

// Round 5
// 16.577 us; speedup vs baseline: 1.4722x; 1.4722x over previous
//
#include <hip/hip_runtime.h>

// DeepFM fused forward, round 5.
// R2's exact proven structure (split-K + LDS combine, inline weight loads),
// with EPB 8->4 and grid 256->512: 16 waves/CU (4/SIMD), 2 blocks/CU so
// barrier drains of one block overlap compute of the other.

#define NF   8
#define ED   16
#define IN0  128   // NF*ED
#define N1   256
#define N2   128
#define N3   64
#define EPB  4     // batch rows per block
#define T    512   // threads per block (8 waves)

__device__ const int g_off[NF] = {0, 50000, 55000, 57000, 58000, 59000, 59500, 59800};

__global__ __launch_bounds__(T, 4) void deepfm_fused(
    const int*   __restrict__ x,     // [B, NF]
    const float* __restrict__ emb,   // [60000, 16]
    const float* __restrict__ wlin,  // [60000]
    const float* __restrict__ blin,  // [1]
    const float* __restrict__ w1,    // [128, 256]
    const float* __restrict__ b1,    // [256]
    const float* __restrict__ w2,    // [256, 128]
    const float* __restrict__ b2,    // [128]
    const float* __restrict__ w3,    // [128, 64]
    const float* __restrict__ b3,    // [64]
    const float* __restrict__ wlast, // [64]
    float*       __restrict__ out)   // [B]
{
    __shared__ float h0[EPB][IN0];     // 2 KB
    __shared__ float h1[EPB][N1];      // 4 KB
    __shared__ float h2[EPB][N2];      // 2 KB
    __shared__ float ps[7 * EPB * N2]; // 14 KB, unioned split-K partials
    __shared__ float base[EPB];

    const int tid = threadIdx.x;
    const int b0  = blockIdx.x * EPB;

    // ---- embedding gather: 512 threads x 1 float (coalesced 16-wide) ----
    {
        const int r = tid >> 7;        // row 0..3
        const int f = (tid >> 4) & 7;  // field 0..7
        const int d = tid & 15;        // dim 0..15
        const int idx = x[(b0 + r) * NF + f] + g_off[f];
        h0[r][f * ED + d] = emb[idx * ED + d];
    }

    // ---- sparse linear: wave 0, lanes 0..31 = 4 rows x 8 fields ----
    if (tid < 32) {
        const int r = tid >> 3, f = tid & 7;
        float lin = wlin[x[(b0 + r) * NF + f] + g_off[f]];
        lin += __shfl_xor(lin, 1);
        lin += __shfl_xor(lin, 2);
        lin += __shfl_xor(lin, 4);
        if (f == 0) base[r] = lin + blin[0];
    }
    __syncthreads();   // B1: h0 + base ready

    // ---- FM second-order: wave 0, 64 lanes = 4 rows x 16 dims ----
    if (tid < 64) {
        const int r = tid >> 4, d = tid & 15;
        float s = 0.0f, ss = 0.0f;
        #pragma unroll
        for (int f = 0; f < NF; ++f) {
            const float v = h0[r][f * ED + d];
            s += v;
            ss = fmaf(v, v, ss);
        }
        float p = 0.5f * (s * s - ss);
        p += __shfl_xor(p, 1);
        p += __shfl_xor(p, 2);
        p += __shfl_xor(p, 4);
        p += __shfl_xor(p, 8);
        if (d == 0) base[r] += p;
    }

    // ---- layer 1: h0[4,128] @ w1[128,256] -> h1[4,256] ----
    // thread: cols c2,c2+1 (c2=(tid&127)*2), K-seg tid>>7 (4 segs x K=32)
    {
        const int c2    = (tid & 127) * 2;
        const int seg   = tid >> 7;
        const int kbase = seg * 32;
        float2 acc[EPB];
        const float2 bb = (seg == 0) ? *(const float2*)(b1 + c2) : make_float2(0.f, 0.f);
        #pragma unroll
        for (int e = 0; e < EPB; ++e) acc[e] = bb;

        #pragma unroll 2
        for (int k0 = 0; k0 < 32; k0 += 4) {
            float4 hv[EPB];
            #pragma unroll
            for (int e = 0; e < EPB; ++e) hv[e] = *(const float4*)(&h0[e][kbase + k0]);
            #pragma unroll
            for (int i = 0; i < 4; ++i) {
                const float2 w = *(const float2*)(w1 + (kbase + k0 + i) * N1 + c2);
                #pragma unroll
                for (int e = 0; e < EPB; ++e) {
                    const float hk = (i == 0) ? hv[e].x : (i == 1) ? hv[e].y
                                   : (i == 2) ? hv[e].z : hv[e].w;
                    acc[e].x = fmaf(hk, w.x, acc[e].x);
                    acc[e].y = fmaf(hk, w.y, acc[e].y);
                }
            }
        }
        if (seg != 0) {
            #pragma unroll
            for (int e = 0; e < EPB; ++e)
                *(float2*)(&ps[(seg - 1) * (EPB * N1) + e * N1 + c2]) = acc[e];
        }
        __syncthreads();   // B2: ps1 ready
        if (seg == 0) {
            #pragma unroll
            for (int e = 0; e < EPB; ++e) {
                float2 v = acc[e];
                #pragma unroll
                for (int s = 0; s < 3; ++s) {
                    const float2 q = *(const float2*)(&ps[s * (EPB * N1) + e * N1 + c2]);
                    v.x += q.x; v.y += q.y;
                }
                h1[e][c2]     = fmaxf(v.x, 0.0f);
                h1[e][c2 + 1] = fmaxf(v.y, 0.0f);
            }
        }
    }
    __syncthreads();   // B3: h1 ready, ps reusable

    // ---- layer 2: h1[4,256] @ w2[256,128] -> h2[4,128] ----
    // thread: cols c2,c2+1 (c2=(tid&63)*2), K-seg tid>>6 (8 segs x K=32)
    {
        const int c2    = (tid & 63) * 2;
        const int seg   = tid >> 6;
        const int kbase = seg * 32;
        float2 acc[EPB];
        #pragma unroll
        for (int e = 0; e < EPB; ++e) acc[e] = make_float2(0.f, 0.f);

        #pragma unroll 2
        for (int k0 = 0; k0 < 32; k0 += 4) {
            float4 hv[EPB];
            #pragma unroll
            for (int e = 0; e < EPB; ++e) hv[e] = *(const float4*)(&h1[e][kbase + k0]);
            #pragma unroll
            for (int i = 0; i < 4; ++i) {
                const float2 w = *(const float2*)(w2 + (kbase + k0 + i) * N2 + c2);
                #pragma unroll
                for (int e = 0; e < EPB; ++e) {
                    const float hk = (i == 0) ? hv[e].x : (i == 1) ? hv[e].y
                                   : (i == 2) ? hv[e].z : hv[e].w;
                    acc[e].x = fmaf(hk, w.x, acc[e].x);
                    acc[e].y = fmaf(hk, w.y, acc[e].y);
                }
            }
        }
        if (seg != 0) {
            #pragma unroll
            for (int e = 0; e < EPB; ++e)
                *(float2*)(&ps[(seg - 1) * (EPB * N2) + e * N2 + c2]) = acc[e];
        }
        __syncthreads();   // B4: ps2 ready
        if (seg == 0) {
            const float2 bb = *(const float2*)(b2 + c2);
            #pragma unroll
            for (int e = 0; e < EPB; ++e) {
                float2 v = acc[e];
                #pragma unroll
                for (int s = 0; s < 7; ++s) {
                    const float2 q = *(const float2*)(&ps[s * (EPB * N2) + e * N2 + c2]);
                    v.x += q.x; v.y += q.y;
                }
                h2[e][c2]     = fmaxf(v.x + bb.x, 0.0f);
                h2[e][c2 + 1] = fmaxf(v.y + bb.y, 0.0f);
            }
        }
    }
    __syncthreads();   // B5: h2 ready, ps reusable

    // ---- layer 3: h2[4,128] @ w3[128,64]; col=tid&63, K-seg tid>>6 (8 x K=16) ----
    {
        const int c     = tid & 63;
        const int seg   = tid >> 6;
        const int kbase = seg * 16;
        float acc[EPB];
        #pragma unroll
        for (int e = 0; e < EPB; ++e) acc[e] = 0.0f;

        #pragma unroll
        for (int k0 = 0; k0 < 16; k0 += 4) {
            float4 hv[EPB];
            #pragma unroll
            for (int e = 0; e < EPB; ++e) hv[e] = *(const float4*)(&h2[e][kbase + k0]);
            #pragma unroll
            for (int i = 0; i < 4; ++i) {
                const float w = w3[(kbase + k0 + i) * N3 + c];
                #pragma unroll
                for (int e = 0; e < EPB; ++e) {
                    const float hk = (i == 0) ? hv[e].x : (i == 1) ? hv[e].y
                                   : (i == 2) ? hv[e].z : hv[e].w;
                    acc[e] = fmaf(hk, w, acc[e]);
                }
            }
        }
        if (seg != 0) {
            #pragma unroll
            for (int e = 0; e < EPB; ++e)
                ps[(seg - 1) * (EPB * N3) + e * N3 + c] = acc[e];
        }
        __syncthreads();   // B6: ps3 ready

        // ---- finale on wave 0 ----
        if (tid < 64) {
            const float bb = b3[c];
            const float wl = wlast[c];
            float t[EPB];
            #pragma unroll
            for (int e = 0; e < EPB; ++e) {
                float v = acc[e] + bb;
                #pragma unroll
                for (int s = 0; s < 7; ++s) v += ps[s * (EPB * N3) + e * N3 + c];
                t[e] = fmaxf(v, 0.0f) * wl;
            }
            #pragma unroll
            for (int off = 1; off < 64; off <<= 1) {
                #pragma unroll
                for (int e = 0; e < EPB; ++e) t[e] += __shfl_xor(t[e], off);
            }
            if (tid == 0) {
                #pragma unroll
                for (int e = 0; e < EPB; ++e) out[b0 + e] = base[e] + t[e];
            }
        }
    }
}

extern "C" void kernel_launch(void* const* d_in, const int* in_sizes, int n_in,
                              void* d_out, int out_size, void* d_ws, size_t ws_size,
                              hipStream_t stream) {
    const int*   x     = (const int*)d_in[0];
    const float* emb   = (const float*)d_in[1];
    const float* wlin  = (const float*)d_in[2];
    const float* blin  = (const float*)d_in[3];
    const float* w1    = (const float*)d_in[4];
    const float* b1    = (const float*)d_in[5];
    const float* w2    = (const float*)d_in[6];
    const float* b2    = (const float*)d_in[7];
    const float* w3    = (const float*)d_in[8];
    const float* b3    = (const float*)d_in[9];
    const float* wlast = (const float*)d_in[10];
    float* out = (float*)d_out;

    const int batch = in_sizes[0] / NF;   // 2048
    dim3 grid(batch / EPB);               // 512 blocks x 512 threads
    deepfm_fused<<<grid, T, 0, stream>>>(x, emb, wlin, blin,
                                         w1, b1, w2, b2, w3, b3, wlast, out);
}

// Round 6
// 13.505 us; speedup vs baseline: 1.8070x; 1.2275x over previous
//
#include <hip/hip_runtime.h>

// DeepFM fused forward, round 6.
// grid=256 x T=1024 (16 waves/block = 4 waves/SIMD); EPB=8 rows/block.
// Traffic unchanged vs R2 (weights read exactly once per block, 75 MB total).
// Deep split-K with all-segs-write-ps + fully distributed combines:
// every phase uses all 1024 threads; per-thread K-chains are 16 (vs 32).

#define NF   8
#define ED   16
#define IN0  128   // NF*ED
#define N1   256
#define N2   128
#define N3   64
#define EPB  8     // batch rows per block
#define T    1024  // threads per block (16 waves)

__device__ const int g_off[NF] = {0, 50000, 55000, 57000, 58000, 59000, 59500, 59800};

__global__ __launch_bounds__(T, 4) void deepfm_fused(
    const int*   __restrict__ x,     // [B, NF]
    const float* __restrict__ emb,   // [60000, 16]
    const float* __restrict__ wlin,  // [60000]
    const float* __restrict__ blin,  // [1]
    const float* __restrict__ w1,    // [128, 256]
    const float* __restrict__ b1,    // [256]
    const float* __restrict__ w2,    // [256, 128]
    const float* __restrict__ b2,    // [128]
    const float* __restrict__ w3,    // [128, 64]
    const float* __restrict__ b3,    // [64]
    const float* __restrict__ wlast, // [64]
    float*       __restrict__ out)   // [B]
{
    __shared__ float h0[EPB][IN0];       // 4 KB
    __shared__ float h1[EPB][N1];        // 8 KB
    __shared__ float h2[EPB][N2];        // 4 KB
    __shared__ float ps[16 * EPB * N2];  // 64 KB, unioned split-K partials
    __shared__ float base[EPB];

    const int tid = threadIdx.x;
    const int b0  = blockIdx.x * EPB;

    // ---- embedding gather: 1024 threads x 1 float, coalesced 16-wide ----
    {
        const int r = tid >> 7;        // row 0..7
        const int f = (tid >> 4) & 7;  // field 0..7
        const int d = tid & 15;        // dim 0..15
        const int idx = x[(b0 + r) * NF + f] + g_off[f];
        h0[r][f * ED + d] = emb[idx * ED + d];
    }

    // ---- sparse linear: wave 0, 64 lanes = 8 rows x 8 fields ----
    if (tid < 64) {
        const int r = tid >> 3, f = tid & 7;
        float lin = wlin[x[(b0 + r) * NF + f] + g_off[f]];
        lin += __shfl_xor(lin, 1);
        lin += __shfl_xor(lin, 2);
        lin += __shfl_xor(lin, 4);
        if (f == 0) base[r] = lin + blin[0];
    }
    __syncthreads();   // B1: h0 + base(linear) ready

    // ---- FM second-order: waves 0-1 = 8 rows x 16 dims ----
    if (tid < 128) {
        const int r = tid >> 4, d = tid & 15;
        float s = 0.0f, ss = 0.0f;
        #pragma unroll
        for (int f = 0; f < NF; ++f) {
            const float v = h0[r][f * ED + d];
            s += v;
            ss = fmaf(v, v, ss);
        }
        float p = 0.5f * (s * s - ss);
        p += __shfl_xor(p, 1);
        p += __shfl_xor(p, 2);
        p += __shfl_xor(p, 4);
        p += __shfl_xor(p, 8);
        if (d == 0) base[r] += p;   // disjoint rows per wave; read after B2+
    }

    // ---- layer 1: h0[8,128] @ w1[128,256]; cols (c2,c2+1), seg tid>>7 (8 x K=16)
    {
        const int c2 = (tid & 127) * 2;
        const int sg = tid >> 7;
        const int kb = sg * 16;
        float2 acc[EPB];
        #pragma unroll
        for (int e = 0; e < EPB; ++e) acc[e] = make_float2(0.f, 0.f);

        #pragma unroll
        for (int k0 = 0; k0 < 16; k0 += 4) {
            float4 hv[EPB];
            #pragma unroll
            for (int e = 0; e < EPB; ++e) hv[e] = *(const float4*)(&h0[e][kb + k0]);
            #pragma unroll
            for (int i = 0; i < 4; ++i) {
                const float2 w = *(const float2*)(w1 + (kb + k0 + i) * N1 + c2);
                #pragma unroll
                for (int e = 0; e < EPB; ++e) {
                    const float hk = (i == 0) ? hv[e].x : (i == 1) ? hv[e].y
                                   : (i == 2) ? hv[e].z : hv[e].w;
                    acc[e].x = fmaf(hk, w.x, acc[e].x);
                    acc[e].y = fmaf(hk, w.y, acc[e].y);
                }
            }
        }
        #pragma unroll
        for (int e = 0; e < EPB; ++e)
            *(float2*)(&ps[(sg * EPB + e) * N1 + c2]) = acc[e];
    }
    __syncthreads();   // B2: ps1 ready

    // ---- combine 1 (distributed): thread -> (r, c2); h1 = relu(sum + b1) ----
    {
        const int r  = tid >> 7;
        const int c2 = (tid & 127) * 2;
        float2 v = *(const float2*)(b1 + c2);
        #pragma unroll
        for (int s = 0; s < 8; ++s) {
            const float2 q = *(const float2*)(&ps[(s * EPB + r) * N1 + c2]);
            v.x += q.x; v.y += q.y;
        }
        h1[r][c2]     = fmaxf(v.x, 0.0f);
        h1[r][c2 + 1] = fmaxf(v.y, 0.0f);
    }
    __syncthreads();   // B3: h1 ready, ps reusable

    // ---- layer 2: h1[8,256] @ w2[256,128]; cols (c2,c2+1), seg tid>>6 (16 x K=16)
    {
        const int c2 = (tid & 63) * 2;
        const int sg = tid >> 6;
        const int kb = sg * 16;
        float2 acc[EPB];
        #pragma unroll
        for (int e = 0; e < EPB; ++e) acc[e] = make_float2(0.f, 0.f);

        #pragma unroll
        for (int k0 = 0; k0 < 16; k0 += 4) {
            float4 hv[EPB];
            #pragma unroll
            for (int e = 0; e < EPB; ++e) hv[e] = *(const float4*)(&h1[e][kb + k0]);
            #pragma unroll
            for (int i = 0; i < 4; ++i) {
                const float2 w = *(const float2*)(w2 + (kb + k0 + i) * N2 + c2);
                #pragma unroll
                for (int e = 0; e < EPB; ++e) {
                    const float hk = (i == 0) ? hv[e].x : (i == 1) ? hv[e].y
                                   : (i == 2) ? hv[e].z : hv[e].w;
                    acc[e].x = fmaf(hk, w.x, acc[e].x);
                    acc[e].y = fmaf(hk, w.y, acc[e].y);
                }
            }
        }
        #pragma unroll
        for (int e = 0; e < EPB; ++e)
            *(float2*)(&ps[(sg * EPB + e) * N2 + c2]) = acc[e];
    }
    __syncthreads();   // B4: ps2 ready

    // ---- combine 2 (distributed): thread -> (r, c); h2 = relu(sum + b2) ----
    {
        const int r = tid >> 7;
        const int c = tid & 127;
        float v = b2[c];
        #pragma unroll
        for (int s = 0; s < 16; ++s) v += ps[(s * EPB + r) * N2 + c];
        h2[r][c] = fmaxf(v, 0.0f);
    }
    __syncthreads();   // B5: h2 ready, ps reusable

    // ---- layer 3: h2[8,128] @ w3[128,64]; col tid&63, seg tid>>6 (16 x K=8) ----
    {
        const int c  = tid & 63;
        const int sg = tid >> 6;
        const int kb = sg * 8;
        float acc[EPB];
        #pragma unroll
        for (int e = 0; e < EPB; ++e) acc[e] = 0.0f;

        #pragma unroll
        for (int k0 = 0; k0 < 8; k0 += 4) {
            float4 hv[EPB];
            #pragma unroll
            for (int e = 0; e < EPB; ++e) hv[e] = *(const float4*)(&h2[e][kb + k0]);
            #pragma unroll
            for (int i = 0; i < 4; ++i) {
                const float w = w3[(kb + k0 + i) * N3 + c];
                #pragma unroll
                for (int e = 0; e < EPB; ++e) {
                    const float hk = (i == 0) ? hv[e].x : (i == 1) ? hv[e].y
                                   : (i == 2) ? hv[e].z : hv[e].w;
                    acc[e] = fmaf(hk, w, acc[e]);
                }
            }
        }
        #pragma unroll
        for (int e = 0; e < EPB; ++e)
            ps[(sg * EPB + e) * N3 + c] = acc[e];
    }
    __syncthreads();   // B6: ps3 ready

    // ---- combine 3 + finale: waves 0-7, wave w == row w ----
    if (tid < 512) {
        const int r = tid >> 6;       // == wave id
        const int c = tid & 63;
        float v = b3[c];
        #pragma unroll
        for (int s = 0; s < 16; ++s) v += ps[(s * EPB + r) * N3 + c];
        float t = fmaxf(v, 0.0f) * wlast[c];
        #pragma unroll
        for (int off = 1; off < 64; off <<= 1) t += __shfl_xor(t, off);
        if (c == 0) out[b0 + r] = base[r] + t;
    }
}

extern "C" void kernel_launch(void* const* d_in, const int* in_sizes, int n_in,
                              void* d_out, int out_size, void* d_ws, size_t ws_size,
                              hipStream_t stream) {
    const int*   x     = (const int*)d_in[0];
    const float* emb   = (const float*)d_in[1];
    const float* wlin  = (const float*)d_in[2];
    const float* blin  = (const float*)d_in[3];
    const float* w1    = (const float*)d_in[4];
    const float* b1    = (const float*)d_in[5];
    const float* w2    = (const float*)d_in[6];
    const float* b2    = (const float*)d_in[7];
    const float* w3    = (const float*)d_in[8];
    const float* b3    = (const float*)d_in[9];
    const float* wlast = (const float*)d_in[10];
    float* out = (float*)d_out;

    const int batch = in_sizes[0] / NF;   // 2048
    dim3 grid(batch / EPB);               // 256 blocks x 1024 threads
    deepfm_fused<<<grid, T, 0, stream>>>(x, emb, wlin, blin,
                                         w1, b1, w2, b2, w3, b3, wlast, out);
}